// Round 2
// baseline (626.685 us; speedup 1.0000x reference)
//
#include <hip/hip_runtime.h>

// ---------------------------------------------------------------------------
// NGNN GCNConv: out = relu((norm_dst * segsum_dst((x*norm_src)[src])) @ W + b) @ fc_W^T + fc_b
// N=100000 nodes, E=1600000 edges, D=128 everywhere.
//
// Pipeline (all on `stream`):
//   0. zero deg_in/deg_out/cursor                (ws)
//   1. degree count (int atomics)
//   2. exclusive scan of deg_in -> csr_off       (3-kernel scan)
//   3. csr fill: csr_src sorted by dst           (int atomics on cursor)
//   4. aggregation: 1 wave per dst node, float2/lane, 4-way edge unroll
//      (4 independent row loads in flight), no float atomics
//      -> writes agg (pre-normalized both sides) into d_out
//   5. fused GEMM: in-place per-32-row tile: relu(agg@W+b) @ fcW^T + fcb
// ---------------------------------------------------------------------------

__global__ void zero_kernel(int* __restrict__ p, int n) {
  int i = blockIdx.x * blockDim.x + threadIdx.x;
  int stride = gridDim.x * blockDim.x;
  for (; i < n; i += stride) p[i] = 0;
}

__global__ void degree_kernel(const int* __restrict__ src, const int* __restrict__ dst,
                              int* __restrict__ deg_out, int* __restrict__ deg_in, int E) {
  int e = blockIdx.x * blockDim.x + threadIdx.x;
  if (e < E) {
    atomicAdd(&deg_out[src[e]], 1);
    atomicAdd(&deg_in[dst[e]], 1);
  }
}

// per-1024-chunk exclusive scan of deg_in -> csr_off (block-local), totals -> bsum
__global__ void scan1_kernel(const int* __restrict__ deg_in, int* __restrict__ csr_off,
                             int* __restrict__ bsum, int N) {
  __shared__ int s[256];
  int tid = threadIdx.x;
  int base = blockIdx.x * 1024 + tid * 4;
  int v0 = 0, v1 = 0, v2 = 0, v3 = 0;
  if (base + 0 < N) v0 = deg_in[base + 0];
  if (base + 1 < N) v1 = deg_in[base + 1];
  if (base + 2 < N) v2 = deg_in[base + 2];
  if (base + 3 < N) v3 = deg_in[base + 3];
  int tot = v0 + v1 + v2 + v3;
  s[tid] = tot;
  __syncthreads();
  for (int off = 1; off < 256; off <<= 1) {
    int add = (tid >= off) ? s[tid - off] : 0;
    __syncthreads();
    s[tid] += add;
    __syncthreads();
  }
  int excl = s[tid] - tot;  // exclusive prefix within block
  if (base + 0 < N) csr_off[base + 0] = excl;
  if (base + 1 < N) csr_off[base + 1] = excl + v0;
  if (base + 2 < N) csr_off[base + 2] = excl + v0 + v1;
  if (base + 3 < N) csr_off[base + 3] = excl + v0 + v1 + v2;
  if (tid == 0) bsum[blockIdx.x] = s[255];
}

// single block: exclusive scan of block sums (nb <= 128)
__global__ void scan2_kernel(int* __restrict__ bsum, int nb) {
  __shared__ int s[128];
  int tid = threadIdx.x;
  int v = (tid < nb) ? bsum[tid] : 0;
  s[tid] = v;
  __syncthreads();
  for (int off = 1; off < 128; off <<= 1) {
    int add = (tid >= off) ? s[tid - off] : 0;
    __syncthreads();
    s[tid] += add;
    __syncthreads();
  }
  bsum[tid] = s[tid] - v;  // exclusive
}

// add block offsets; compute both norm vectors
__global__ void scan3_norm_kernel(int* __restrict__ csr_off, const int* __restrict__ bsum,
                                  const int* __restrict__ deg_out, const int* __restrict__ deg_in,
                                  float* __restrict__ norm_src, float* __restrict__ norm_dst,
                                  int N) {
  int i = blockIdx.x * blockDim.x + threadIdx.x;
  if (i < N) {
    csr_off[i] += bsum[i >> 10];
    int dgo = deg_out[i]; if (dgo < 1) dgo = 1;
    int dgi = deg_in[i];  if (dgi < 1) dgi = 1;
    norm_src[i] = 1.0f / sqrtf((float)dgo);
    norm_dst[i] = 1.0f / sqrtf((float)dgi);
  }
}

__global__ void fill_kernel(const int* __restrict__ src, const int* __restrict__ dst,
                            const int* __restrict__ csr_off, int* __restrict__ cursor,
                            int* __restrict__ csr_src, int E) {
  int e = blockIdx.x * blockDim.x + threadIdx.x;
  if (e < E) {
    int d = dst[e];
    int p = atomicAdd(&cursor[d], 1);
    csr_src[csr_off[d] + p] = src[e];
  }
}

// 1 wave per dst node; lane holds float2 of the 128-wide row.
// 4-way edge unroll: 4 independent index/norm/row loads in flight per wave.
__global__ __launch_bounds__(256) void agg_kernel(
    const float* __restrict__ x, const int* __restrict__ csr_src,
    const int* __restrict__ csr_off, const int* __restrict__ deg_in,
    const float* __restrict__ norm_src, const float* __restrict__ norm_dst,
    float* __restrict__ out, int N) {
  int wid = threadIdx.x >> 6;
  int lane = threadIdx.x & 63;
  int v = blockIdx.x * 4 + wid;
  if (v >= N) return;
  int start = csr_off[v];
  int cnt = deg_in[v];
  int end = start + cnt;
  const float2* __restrict__ x2 = (const float2*)x;

  float2 a0, a1, a2, a3;
  a0.x = a0.y = a1.x = a1.y = a2.x = a2.y = a3.x = a3.y = 0.f;

  int e = start;
  for (; e + 4 <= end; e += 4) {
    int s0 = csr_src[e + 0];
    int s1 = csr_src[e + 1];
    int s2 = csr_src[e + 2];
    int s3 = csr_src[e + 3];
    float n0 = norm_src[s0];
    float n1 = norm_src[s1];
    float n2 = norm_src[s2];
    float n3 = norm_src[s3];
    float2 v0 = x2[(size_t)s0 * 64 + lane];
    float2 v1 = x2[(size_t)s1 * 64 + lane];
    float2 v2 = x2[(size_t)s2 * 64 + lane];
    float2 v3 = x2[(size_t)s3 * 64 + lane];
    a0.x += v0.x * n0; a0.y += v0.y * n0;
    a1.x += v1.x * n1; a1.y += v1.y * n1;
    a2.x += v2.x * n2; a2.y += v2.y * n2;
    a3.x += v3.x * n3; a3.y += v3.y * n3;
  }
  for (; e < end; ++e) {
    int s = csr_src[e];
    float n = norm_src[s];
    float2 xv = x2[(size_t)s * 64 + lane];
    a0.x += xv.x * n; a0.y += xv.y * n;
  }

  float nd = norm_dst[v];
  float2 r;
  r.x = ((a0.x + a1.x) + (a2.x + a3.x)) * nd;
  r.y = ((a0.y + a1.y) + (a2.y + a3.y)) * nd;
  ((float2*)out)[(size_t)v * 64 + lane] = r;
}

// Fused: io (agg rows, in-place) -> relu(agg@W + b) -> @ fcW^T + fcb
// 32-node tile per 256-thread block. LDS = 16K(aggT)+16K(hT)+32K(fwT) = 64KB.
__global__ __launch_bounds__(256, 2) void gemm_fused_kernel(
    float* __restrict__ io, const float* __restrict__ W, const float* __restrict__ b,
    const float* __restrict__ fcW, const float* __restrict__ fcb, int N) {
  __shared__ float aggT[32][128];
  __shared__ float hT[32][128];
  __shared__ float fwT[128][64];  // fcW^T half, XOR-swizzled columns

  int t = threadIdx.x;
  int row0 = blockIdx.x * 32;
  size_t base = (size_t)row0 * 128;

  // stage 32x128 agg tile (coalesced)
#pragma unroll
  for (int r = 0; r < 16; ++r) {
    int idx = r * 256 + t;
    int rr = idx >> 7;
    float val = (row0 + rr < N) ? io[base + idx] : 0.f;
    aggT[rr][idx & 127] = val;
  }
  __syncthreads();

  // ---- phase 1: hT = relu(aggT @ W + b); W read from global (L1/L2-resident)
  {
    int tj = t & 31;   // j0 = 4*tj
    int ti = t >> 5;   // i0 = 4*ti
    int j0 = 4 * tj, i0 = 4 * ti;
    float acc[4][4];
    const float4 b4 = *(const float4*)&b[j0];
#pragma unroll
    for (int q = 0; q < 4; ++q) {
      acc[q][0] = b4.x; acc[q][1] = b4.y; acc[q][2] = b4.z; acc[q][3] = b4.w;
    }
    for (int k = 0; k < 128; k += 4) {
      float4 a0 = *(const float4*)&aggT[i0 + 0][k];
      float4 a1 = *(const float4*)&aggT[i0 + 1][k];
      float4 a2 = *(const float4*)&aggT[i0 + 2][k];
      float4 a3 = *(const float4*)&aggT[i0 + 3][k];
      float4 w0 = *(const float4*)&W[(size_t)(k + 0) * 128 + j0];
      float4 w1 = *(const float4*)&W[(size_t)(k + 1) * 128 + j0];
      float4 w2 = *(const float4*)&W[(size_t)(k + 2) * 128 + j0];
      float4 w3 = *(const float4*)&W[(size_t)(k + 3) * 128 + j0];
#define P1(aq, q)                                                         \
      acc[q][0] += aq.x * w0.x + aq.y * w1.x + aq.z * w2.x + aq.w * w3.x; \
      acc[q][1] += aq.x * w0.y + aq.y * w1.y + aq.z * w2.y + aq.w * w3.y; \
      acc[q][2] += aq.x * w0.z + aq.y * w1.z + aq.z * w2.z + aq.w * w3.z; \
      acc[q][3] += aq.x * w0.w + aq.y * w1.w + aq.z * w2.w + aq.w * w3.w;
      P1(a0, 0) P1(a1, 1) P1(a2, 2) P1(a3, 3)
#undef P1
    }
#pragma unroll
    for (int q = 0; q < 4; ++q) {
      float4 h4;
      h4.x = fmaxf(acc[q][0], 0.f);
      h4.y = fmaxf(acc[q][1], 0.f);
      h4.z = fmaxf(acc[q][2], 0.f);
      h4.w = fmaxf(acc[q][3], 0.f);
      *(float4*)&hT[i0 + q][j0] = h4;
    }
  }
  __syncthreads();

  // ---- phase 2: out = hT @ fcW^T + fcb, two 64-col halves with swizzled LDS
  int tj2 = t & 31;  // j0 = 2*tj2 within half
  int ti2 = t >> 5;  // i0 = 4*ti2
  int i0 = 4 * ti2;
  for (int half = 0; half < 2; ++half) {
    // stage fcW^T for this half: fwT[k][j ^ (k&31)] = fcW[half*64 + j][k]
#pragma unroll
    for (int r = 0; r < 32; ++r) {
      int idx = r * 256 + t;      // 0..8191
      int row = idx >> 7;         // j within half (0..63)
      int col = idx & 127;        // k
      fwT[col][row ^ (col & 31)] = fcW[(size_t)(half * 64 + row) * 128 + col];
    }
    __syncthreads();

    float acc[4][2];
    float bj0 = fcb[half * 64 + 2 * tj2 + 0];
    float bj1 = fcb[half * 64 + 2 * tj2 + 1];
#pragma unroll
    for (int q = 0; q < 4; ++q) { acc[q][0] = bj0; acc[q][1] = bj1; }

    for (int k = 0; k < 128; k += 4) {
      float4 h0 = *(const float4*)&hT[i0 + 0][k];
      float4 h1 = *(const float4*)&hT[i0 + 1][k];
      float4 h2 = *(const float4*)&hT[i0 + 2][k];
      float4 h3 = *(const float4*)&hT[i0 + 3][k];
#pragma unroll
      for (int kk = 0; kk < 4; ++kk) {
        int kc = k + kk;
        int c = kc & 31;
        float w0 = fwT[kc][(2 * tj2 + 0) ^ c];
        float w1 = fwT[kc][(2 * tj2 + 1) ^ c];
        float hv0 = (kk == 0) ? h0.x : (kk == 1) ? h0.y : (kk == 2) ? h0.z : h0.w;
        float hv1 = (kk == 0) ? h1.x : (kk == 1) ? h1.y : (kk == 2) ? h1.z : h1.w;
        float hv2 = (kk == 0) ? h2.x : (kk == 1) ? h2.y : (kk == 2) ? h2.z : h2.w;
        float hv3 = (kk == 0) ? h3.x : (kk == 1) ? h3.y : (kk == 2) ? h3.z : h3.w;
        acc[0][0] += hv0 * w0; acc[0][1] += hv0 * w1;
        acc[1][0] += hv1 * w0; acc[1][1] += hv1 * w1;
        acc[2][0] += hv2 * w0; acc[2][1] += hv2 * w1;
        acc[3][0] += hv3 * w0; acc[3][1] += hv3 * w1;
      }
    }
#pragma unroll
    for (int q = 0; q < 4; ++q) {
      int rr = i0 + q;
      if (row0 + rr < N) {
        float2 o2; o2.x = acc[q][0]; o2.y = acc[q][1];
        *(float2*)&io[base + (size_t)rr * 128 + half * 64 + 2 * tj2] = o2;
      }
    }
    __syncthreads();
  }
}

extern "C" void kernel_launch(void* const* d_in, const int* in_sizes, int n_in,
                              void* d_out, int out_size, void* d_ws, size_t ws_size,
                              hipStream_t stream) {
  const float* x   = (const float*)d_in[0];
  const int* src   = (const int*)d_in[1];
  const int* dst   = (const int*)d_in[2];
  const float* W   = (const float*)d_in[3];
  const float* b   = (const float*)d_in[4];
  const float* fcW = (const float*)d_in[5];
  const float* fcb = (const float*)d_in[6];
  float* out = (float*)d_out;

  const int N = in_sizes[0] / 128;
  const int E = in_sizes[1];

  // ws layout (ints), NA = N rounded up to 1024
  const int NA = ((N + 1023) / 1024) * 1024;
  int* wsi = (int*)d_ws;
  int*   deg_in   = wsi + 0 * (size_t)NA;
  int*   deg_out  = wsi + 1 * (size_t)NA;
  int*   cursor   = wsi + 2 * (size_t)NA;
  float* norm_src = (float*)(wsi + 3 * (size_t)NA);
  float* norm_dst = (float*)(wsi + 4 * (size_t)NA);
  int*   csr_off  = wsi + 5 * (size_t)NA;
  int*   bsum     = wsi + 6 * (size_t)NA;          // 256 ints
  int*   csr_src  = wsi + 6 * (size_t)NA + 256;    // E ints

  const int NB1 = (N + 1023) / 1024;  // 98 blocks for N=100000 (must be <=128)

  // 0. zero deg_in, deg_out, cursor (contiguous 3*NA ints)
  zero_kernel<<<512, 256, 0, stream>>>(wsi, 3 * NA);
  // 1. degrees
  degree_kernel<<<(E + 255) / 256, 256, 0, stream>>>(src, dst, deg_out, deg_in, E);
  // 2. scan deg_in -> csr_off
  scan1_kernel<<<NB1, 256, 0, stream>>>(deg_in, csr_off, bsum, N);
  scan2_kernel<<<1, 128, 0, stream>>>(bsum, NB1);
  scan3_norm_kernel<<<(N + 255) / 256, 256, 0, stream>>>(csr_off, bsum, deg_out, deg_in,
                                                         norm_src, norm_dst, N);
  // 3. fill CSR (src indices grouped by dst)
  fill_kernel<<<(E + 255) / 256, 256, 0, stream>>>(src, dst, csr_off, cursor, csr_src, E);
  // 4. aggregate: one wave per node -> d_out holds normalized agg
  agg_kernel<<<(N + 3) / 4, 256, 0, stream>>>(x, csr_src, csr_off, deg_in,
                                              norm_src, norm_dst, out, N);
  // 5. fused GEMMs in-place on d_out
  gemm_fused_kernel<<<(N + 31) / 32, 256, 0, stream>>>(out, W, b, fcW, fcb, N);
}